// Round 1
// baseline (1168.278 us; speedup 1.0000x reference)
//
#include <hip/hip_runtime.h>

typedef short bf16x8 __attribute__((ext_vector_type(8)));
typedef float f32x4 __attribute__((ext_vector_type(4)));

#define LN10000_32 0.2878231406211853f  // ln(10000)/32

__device__ __forceinline__ unsigned short f2bf(float f) {
  union { float f; unsigned int u; } v; v.f = f;
  unsigned int r = v.u + 0x7fffu + ((v.u >> 16) & 1u);
  return (unsigned short)(r >> 16);
}
__device__ __forceinline__ float bf2f(unsigned short h) {
  union { unsigned int u; float f; } v; v.u = ((unsigned int)h) << 16;
  return v.f;
}

// ---------------- stage 16B/lane into LDS (wave-uniform lds base) -------------
__device__ __forceinline__ void stage16(const unsigned short* g, unsigned short* lds_base, int lane) {
#if __has_builtin(__builtin_amdgcn_global_load_lds)
  (void)lane;
  __builtin_amdgcn_global_load_lds((const __attribute__((address_space(1))) void*)g,
                                   (__attribute__((address_space(3))) void*)lds_base,
                                   16, 0, 0);
#else
  *(bf16x8*)((char*)lds_base + lane * 16) = *(const bf16x8*)g;
#endif
}

// ---------------- min/max of the two x_ref_attn_map rows ---------------------
__global__ void minmax_kernel(const float* __restrict__ xmap, float* __restrict__ mm) {
  __shared__ float red[4][256];
  int t = threadIdx.x;
  float mn0 = 3.4e38f, mx0 = -3.4e38f, mn1 = 3.4e38f, mx1 = -3.4e38f;
  for (int i = t; i < 32760; i += 256) {
    float a = xmap[i];          mn0 = fminf(mn0, a); mx0 = fmaxf(mx0, a);
    float b = xmap[32760 + i];  mn1 = fminf(mn1, b); mx1 = fmaxf(mx1, b);
  }
  red[0][t] = mn0; red[1][t] = mx0; red[2][t] = mn1; red[3][t] = mx1;
  __syncthreads();
  for (int s = 128; s > 0; s >>= 1) {
    if (t < s) {
      red[0][t] = fminf(red[0][t], red[0][t + s]);
      red[1][t] = fmaxf(red[1][t], red[1][t + s]);
      red[2][t] = fminf(red[2][t], red[2][t + s]);
      red[3][t] = fmaxf(red[3][t], red[3][t + s]);
    }
    __syncthreads();
  }
  if (t == 0) { mm[0] = red[0][0]; mm[1] = red[1][0]; mm[2] = red[2][0]; mm[3] = red[3][0]; }
}

// ---------------- normalized position -> cos/sin table (32760 x 32) ----------
__global__ void pos_table_kernel(const float* __restrict__ xmap, const float* __restrict__ mm,
                                 float2* __restrict__ tab) {
  int n = blockIdx.x * 256 + threadIdx.x;
  if (n >= 32760) return;
  float m0 = xmap[n], m1 = xmap[32760 + n];
  float pos;
  if (m1 > m0) pos = (m1 - mm[2]) / (mm[3] - mm[2] + 1e-8f) * 4.0f + 20.0f;  // human2 -> [20,24]
  else         pos = (m0 - mm[0]) / (mm[1] - mm[0] + 1e-8f) * 4.0f;          // human1 -> [0,4]
  #pragma unroll
  for (int j = 0; j < 32; j++) {
    float invf = __expf(-(float)j * LN10000_32);
    float f = pos * invf;
    float s, c;
    sincosf(f, &s, &c);
    tab[(long)n * 32 + j] = make_float2(c, s);
  }
}

// ---------------- casts -------------------------------------------------------
__global__ void cast_x_kernel(const float* __restrict__ src, unsigned short* __restrict__ dst) {
  int r = blockIdx.x;            // 0..32767 (pad rows 32760..32767 -> 0)
  int c = threadIdx.x * 8;
  bf16x8 o;
  if (r < 32760) {
    const float4* s = (const float4*)(src + (long)r * 2048 + c);
    float4 a = s[0], b = s[1];
    o[0] = (short)f2bf(a.x); o[1] = (short)f2bf(a.y); o[2] = (short)f2bf(a.z); o[3] = (short)f2bf(a.w);
    o[4] = (short)f2bf(b.x); o[5] = (short)f2bf(b.y); o[6] = (short)f2bf(b.z); o[7] = (short)f2bf(b.w);
  } else {
    #pragma unroll
    for (int t = 0; t < 8; t++) o[t] = 0;
  }
  *(bf16x8*)(dst + (long)r * 2048 + c) = o;
}

__global__ void cast_flat_kernel(const float* __restrict__ src, unsigned short* __restrict__ dst, long n8) {
  long i = (long)blockIdx.x * 256 + threadIdx.x;
  if (i >= n8) return;
  const float4* s = (const float4*)(src + i * 8);
  float4 a = s[0], b = s[1];
  bf16x8 o;
  o[0] = (short)f2bf(a.x); o[1] = (short)f2bf(a.y); o[2] = (short)f2bf(a.z); o[3] = (short)f2bf(a.w);
  o[4] = (short)f2bf(b.x); o[5] = (short)f2bf(b.y); o[6] = (short)f2bf(b.z); o[7] = (short)f2bf(b.w);
  *(bf16x8*)(dst + i * 8) = o;
}

__global__ void cast_ehs_kernel(const float* __restrict__ src, unsigned short* __restrict__ dst) {
  int idx = blockIdx.x * 256 + threadIdx.x;  // 768*96 = 73728 threads
  int r = idx / 96, c = (idx % 96) * 8;
  bf16x8 o;
  if (r < 672) {
    const float4* s = (const float4*)(src + (long)r * 768 + c);
    float4 a = s[0], b = s[1];
    o[0] = (short)f2bf(a.x); o[1] = (short)f2bf(a.y); o[2] = (short)f2bf(a.z); o[3] = (short)f2bf(a.w);
    o[4] = (short)f2bf(b.x); o[5] = (short)f2bf(b.y); o[6] = (short)f2bf(b.z); o[7] = (short)f2bf(b.w);
  } else {
    #pragma unroll
    for (int t = 0; t < 8; t++) o[t] = 0;
  }
  *(bf16x8*)(dst + (long)r * 768 + c) = o;
}

// ---------------- GEMM: C[m,n] = sum_k A[m,k]*B[n,k] + bias[n] ----------------
// 128x128 tile, BK=32, 4 waves (2x2), mfma_f32_16x16x32_bf16, m97-style.
template <int OUTF>
__global__ __launch_bounds__(256, 2)
void gemm_bt(const unsigned short* __restrict__ A, const unsigned short* __restrict__ B,
             const float* __restrict__ bias, void* __restrict__ C,
             int M, int N, int K, int M_valid) {
  __shared__ unsigned short As[128 * 32];
  __shared__ unsigned short Bs[128 * 32];
  const int m0 = blockIdx.x * 128;
  const int n0 = blockIdx.y * 128;
  const int tid = threadIdx.x;
  const int wave = tid >> 6;
  const int lane = tid & 63;
  const int wr = wave >> 1, wc = wave & 1;
  const int lrow = lane >> 2, lcol = lane & 3;

  f32x4 acc[4][4];
  #pragma unroll
  for (int i = 0; i < 4; i++)
    #pragma unroll
    for (int j = 0; j < 4; j++) acc[i][j] = (f32x4){0.f, 0.f, 0.f, 0.f};

  const unsigned short* gA = A + (long)(m0 + wave * 32 + lrow) * K + lcol * 8;
  const unsigned short* gB = B + (long)(n0 + wave * 32 + lrow) * K + lcol * 8;
  unsigned short* lA0 = &As[wave * 1024];
  unsigned short* lA1 = &As[wave * 1024 + 512];
  unsigned short* lB0 = &Bs[wave * 1024];
  unsigned short* lB1 = &Bs[wave * 1024 + 512];

  for (int k0 = 0; k0 < K; k0 += 32) {
    stage16(gA + k0, lA0, lane);
    stage16(gA + k0 + 16 * K, lA1, lane);
    stage16(gB + k0, lB0, lane);
    stage16(gB + k0 + 16 * K, lB1, lane);
    __syncthreads();
    bf16x8 af[4], bfr[4];
    const int kq = (lane >> 4) * 8;
    const int rr = lane & 15;
    #pragma unroll
    for (int mi = 0; mi < 4; mi++) af[mi] = *(const bf16x8*)&As[(wr * 64 + mi * 16 + rr) * 32 + kq];
    #pragma unroll
    for (int ni = 0; ni < 4; ni++) bfr[ni] = *(const bf16x8*)&Bs[(wc * 64 + ni * 16 + rr) * 32 + kq];
    #pragma unroll
    for (int mi = 0; mi < 4; mi++)
      #pragma unroll
      for (int ni = 0; ni < 4; ni++)
        acc[mi][ni] = __builtin_amdgcn_mfma_f32_16x16x32_bf16(af[mi], bfr[ni], acc[mi][ni], 0, 0, 0);
    __syncthreads();
  }

  const int colL = lane & 15, rq = (lane >> 4) * 4;
  #pragma unroll
  for (int mi = 0; mi < 4; mi++) {
    #pragma unroll
    for (int ni = 0; ni < 4; ni++) {
      int col = n0 + wc * 64 + ni * 16 + colL;
      float bv = bias[col];
      #pragma unroll
      for (int r = 0; r < 4; r++) {
        int row = m0 + wr * 64 + mi * 16 + rq + r;
        if (row < M_valid) {
          float v = acc[mi][ni][r] + bv;
          if (OUTF) ((float*)C)[(long)row * N + col] = v;
          else      ((unsigned short*)C)[(long)row * N + col] = f2bf(v);
        }
      }
    }
  }
}

// ---------------- RoPE on Q (in place, table-driven) --------------------------
__global__ void rope_q_kernel(unsigned short* __restrict__ q, const float2* __restrict__ tab) {
  int r = blockIdx.x;           // 0..32759
  int c = threadIdx.x * 8;      // 0..2040
  unsigned short* p = q + (long)r * 2048 + c;
  bf16x8 v = *(const bf16x8*)p;
  int jb = (c & 63) >> 1;       // multiple of 4
  float4 t0 = *(const float4*)&tab[(long)r * 32 + jb];
  float4 t1 = *(const float4*)&tab[(long)r * 32 + jb + 2];
  float cs[4] = {t0.x, t0.z, t1.x, t1.z};
  float sn[4] = {t0.y, t0.w, t1.y, t1.w};
  bf16x8 o;
  #pragma unroll
  for (int t = 0; t < 4; t++) {
    float x1 = bf2f((unsigned short)v[2 * t]);
    float x2 = bf2f((unsigned short)v[2 * t + 1]);
    o[2 * t]     = (short)f2bf(x1 * cs[t] - x2 * sn[t]);
    o[2 * t + 1] = (short)f2bf(x1 * sn[t] + x2 * cs[t]);
  }
  *(bf16x8*)p = o;
}

// ---------------- RoPE on K (in place, fixed positions 2 / 22) ----------------
__global__ void rope_k_kernel(unsigned short* __restrict__ kv) {
  int r = blockIdx.x;           // 0..671 (row = b*32 + a)
  int c = threadIdx.x * 8;      // only k half: cols 0..2047
  float pos = ((r & 31) < 16) ? 2.0f : 22.0f;
  unsigned short* p = kv + (long)r * 4096 + c;
  bf16x8 v = *(const bf16x8*)p;
  int jb = (c & 63) >> 1;
  bf16x8 o;
  #pragma unroll
  for (int t = 0; t < 4; t++) {
    float invf = __expf(-(float)(jb + t) * LN10000_32);
    float f = pos * invf;
    float s_, c_;
    sincosf(f, &s_, &c_);
    float x1 = bf2f((unsigned short)v[2 * t]);
    float x2 = bf2f((unsigned short)v[2 * t + 1]);
    o[2 * t]     = (short)f2bf(x1 * c_ - x2 * s_);
    o[2 * t + 1] = (short)f2bf(x1 * s_ + x2 * c_);
  }
  *(bf16x8*)p = o;
}

// ---------------- attention: 32 keys, VALU, in-place on q buffer --------------
__global__ __launch_bounds__(256)
void attn_kernel(const unsigned short* __restrict__ kv, unsigned short* __restrict__ q) {
  __shared__ float Ks[2048];
  __shared__ float Vs[2048];
  const int bh = blockIdx.y;
  const int b = bh >> 5, h = bh & 31;
  const int tid = threadIdx.x;
  for (int i = tid; i < 2048; i += 256) {
    int a = i >> 6, d = i & 63;
    long off = ((long)(b * 32 + a)) * 4096 + h * 64 + d;
    Ks[i] = bf2f(kv[off]);
    Vs[i] = bf2f(kv[off + 2048]);
  }
  __syncthreads();
  int s = blockIdx.x * 256 + tid;
  if (s >= 1560) return;
  unsigned short* qp = q + ((long)(b * 1560 + s)) * 2048 + h * 64;
  float qr[64];
  #pragma unroll
  for (int i = 0; i < 8; i++) {
    bf16x8 v = *(const bf16x8*)(qp + i * 8);
    #pragma unroll
    for (int j = 0; j < 8; j++) qr[i * 8 + j] = bf2f((unsigned short)v[j]);
  }
  float sc[32];
  float mx = -3.4e38f;
  #pragma unroll
  for (int a = 0; a < 32; a++) {
    float acc = 0.f;
    #pragma unroll
    for (int d = 0; d < 64; d++) acc = fmaf(qr[d], Ks[a * 64 + d], acc);
    acc *= 0.125f;
    sc[a] = acc;
    mx = fmaxf(mx, acc);
  }
  float sum = 0.f;
  #pragma unroll
  for (int a = 0; a < 32; a++) { float e = __expf(sc[a] - mx); sc[a] = e; sum += e; }
  float inv = 1.f / sum;
  float outr[64];
  #pragma unroll
  for (int d = 0; d < 64; d++) outr[d] = 0.f;
  #pragma unroll
  for (int a = 0; a < 32; a++) {
    float p = sc[a] * inv;
    #pragma unroll
    for (int d = 0; d < 64; d++) outr[d] = fmaf(p, Vs[a * 64 + d], outr[d]);
  }
  #pragma unroll
  for (int i = 0; i < 8; i++) {
    bf16x8 v;
    #pragma unroll
    for (int j = 0; j < 8; j++) v[j] = (short)f2bf(outr[i * 8 + j]);
    *(bf16x8*)(qp + i * 8) = v;
  }
}

// ---------------- launch ------------------------------------------------------
extern "C" void kernel_launch(void* const* d_in, const int* in_sizes, int n_in,
                              void* d_out, int out_size, void* d_ws, size_t ws_size,
                              hipStream_t stream) {
  const float* x      = (const float*)d_in[0];
  const float* ehs    = (const float*)d_in[1];
  const float* xmap   = (const float*)d_in[2];
  const float* q_w    = (const float*)d_in[3];
  const float* q_b    = (const float*)d_in[4];
  const float* kv_w   = (const float*)d_in[5];
  const float* kv_b   = (const float*)d_in[6];
  const float* proj_w = (const float*)d_in[7];
  const float* proj_b = (const float*)d_in[8];
  float* out = (float*)d_out;

  // ws layout (bytes)
  char* ws = (char*)d_ws;
  float*          mm    = (float*)(ws + 0);            // 4 floats
  float2*         tab   = (float2*)(ws + 256);         // 32768*32*8 = 8,388,608
  unsigned short* qbuf  = (unsigned short*)(ws + 8388864);    // 32768*2048*2 = 134,217,728
  unsigned short* kvbuf = (unsigned short*)(ws + 142606592);  // 768*4096*2   = 6,291,456
  unsigned short* ehsb  = (unsigned short*)(ws + 148898048);  // 768*768*2    = 1,179,648
  unsigned short* qwb   = (unsigned short*)(ws + 150077696);  // 2048*2048*2  = 8,388,608
  unsigned short* kvwb  = (unsigned short*)(ws + 158466304);  // 4096*768*2   = 6,291,456
  unsigned short* pwb   = (unsigned short*)(ws + 164757760);  // 2048*2048*2  = 8,388,608
  unsigned short* xb    = (unsigned short*)d_out;             // x as bf16 (dead before final GEMM)

  minmax_kernel<<<1, 256, 0, stream>>>(xmap, mm);
  pos_table_kernel<<<128, 256, 0, stream>>>(xmap, mm, tab);
  cast_x_kernel<<<32768, 256, 0, stream>>>(x, xb);
  cast_flat_kernel<<<2048, 256, 0, stream>>>(q_w, qwb, 524288);
  cast_flat_kernel<<<1536, 256, 0, stream>>>(kv_w, kvwb, 393216);
  cast_flat_kernel<<<2048, 256, 0, stream>>>(proj_w, pwb, 524288);
  cast_ehs_kernel<<<288, 256, 0, stream>>>(ehs, ehsb);

  gemm_bt<0><<<dim3(256, 16), 256, 0, stream>>>(xb, qwb, q_b, qbuf, 32768, 2048, 2048, 32768);
  gemm_bt<0><<<dim3(6, 32), 256, 0, stream>>>(ehsb, kvwb, kv_b, kvbuf, 768, 4096, 768, 768);

  rope_q_kernel<<<32760, 256, 0, stream>>>(qbuf, tab);
  rope_k_kernel<<<672, 256, 0, stream>>>(kvbuf);

  attn_kernel<<<dim3(7, 672), 256, 0, stream>>>(kvbuf, qbuf);

  gemm_bt<1><<<dim3(256, 16), 256, 0, stream>>>(qbuf, pwb, proj_b, out, 32768, 2048, 2048, 32760);
}

// Round 2
// 1125.805 us; speedup vs baseline: 1.0377x; 1.0377x over previous
//
#include <hip/hip_runtime.h>

typedef short bf16x8 __attribute__((ext_vector_type(8)));
typedef float f32x4 __attribute__((ext_vector_type(4)));

#define LN10000_32 0.2878231406211853f  // ln(10000)/32

__device__ __forceinline__ unsigned short f2bf(float f) {
  union { float f; unsigned int u; } v; v.f = f;
  unsigned int r = v.u + 0x7fffu + ((v.u >> 16) & 1u);
  return (unsigned short)(r >> 16);
}
__device__ __forceinline__ float bf2f(unsigned short h) {
  union { unsigned int u; float f; } v; v.u = ((unsigned int)h) << 16;
  return v.f;
}

// ---------------- stage 16B/lane into LDS (wave-uniform lds base) -------------
__device__ __forceinline__ void stage16(const unsigned short* g, unsigned short* lds_base, int lane) {
#if __has_builtin(__builtin_amdgcn_global_load_lds)
  (void)lane;
  __builtin_amdgcn_global_load_lds((const __attribute__((address_space(1))) void*)g,
                                   (__attribute__((address_space(3))) void*)lds_base,
                                   16, 0, 0);
#else
  *(bf16x8*)((char*)lds_base + lane * 16) = *(const bf16x8*)g;
#endif
}

// ---------------- min/max of the two x_ref_attn_map rows ---------------------
__global__ void minmax_kernel(const float* __restrict__ xmap, float* __restrict__ mm) {
  __shared__ float red[4][256];
  int t = threadIdx.x;
  float mn0 = 3.4e38f, mx0 = -3.4e38f, mn1 = 3.4e38f, mx1 = -3.4e38f;
  for (int i = t; i < 32760; i += 256) {
    float a = xmap[i];          mn0 = fminf(mn0, a); mx0 = fmaxf(mx0, a);
    float b = xmap[32760 + i];  mn1 = fminf(mn1, b); mx1 = fmaxf(mx1, b);
  }
  red[0][t] = mn0; red[1][t] = mx0; red[2][t] = mn1; red[3][t] = mx1;
  __syncthreads();
  for (int s = 128; s > 0; s >>= 1) {
    if (t < s) {
      red[0][t] = fminf(red[0][t], red[0][t + s]);
      red[1][t] = fmaxf(red[1][t], red[1][t + s]);
      red[2][t] = fminf(red[2][t], red[2][t + s]);
      red[3][t] = fmaxf(red[3][t], red[3][t + s]);
    }
    __syncthreads();
  }
  if (t == 0) { mm[0] = red[0][0]; mm[1] = red[1][0]; mm[2] = red[2][0]; mm[3] = red[3][0]; }
}

// ---------------- normalized position -> cos/sin table (32760 x 32) ----------
__global__ void pos_table_kernel(const float* __restrict__ xmap, const float* __restrict__ mm,
                                 float2* __restrict__ tab) {
  int n = blockIdx.x * 256 + threadIdx.x;
  if (n >= 32760) return;
  float m0 = xmap[n], m1 = xmap[32760 + n];
  float pos;
  if (m1 > m0) pos = (m1 - mm[2]) / (mm[3] - mm[2] + 1e-8f) * 4.0f + 20.0f;  // human2 -> [20,24]
  else         pos = (m0 - mm[0]) / (mm[1] - mm[0] + 1e-8f) * 4.0f;          // human1 -> [0,4]
  #pragma unroll
  for (int j = 0; j < 32; j++) {
    float invf = __expf(-(float)j * LN10000_32);
    float f = pos * invf;
    float s, c;
    sincosf(f, &s, &c);
    tab[(long)n * 32 + j] = make_float2(c, s);
  }
}

// ---------------- casts -------------------------------------------------------
__global__ void cast_x_kernel(const float* __restrict__ src, unsigned short* __restrict__ dst) {
  int r = blockIdx.x;            // 0..32767 (pad rows 32760..32767 -> 0)
  int c = threadIdx.x * 8;
  bf16x8 o;
  if (r < 32760) {
    const float4* s = (const float4*)(src + (long)r * 2048 + c);
    float4 a = s[0], b = s[1];
    o[0] = (short)f2bf(a.x); o[1] = (short)f2bf(a.y); o[2] = (short)f2bf(a.z); o[3] = (short)f2bf(a.w);
    o[4] = (short)f2bf(b.x); o[5] = (short)f2bf(b.y); o[6] = (short)f2bf(b.z); o[7] = (short)f2bf(b.w);
  } else {
    #pragma unroll
    for (int t = 0; t < 8; t++) o[t] = 0;
  }
  *(bf16x8*)(dst + (long)r * 2048 + c) = o;
}

__global__ void cast_flat_kernel(const float* __restrict__ src, unsigned short* __restrict__ dst, long n8) {
  long i = (long)blockIdx.x * 256 + threadIdx.x;
  if (i >= n8) return;
  const float4* s = (const float4*)(src + i * 8);
  float4 a = s[0], b = s[1];
  bf16x8 o;
  o[0] = (short)f2bf(a.x); o[1] = (short)f2bf(a.y); o[2] = (short)f2bf(a.z); o[3] = (short)f2bf(a.w);
  o[4] = (short)f2bf(b.x); o[5] = (short)f2bf(b.y); o[6] = (short)f2bf(b.z); o[7] = (short)f2bf(b.w);
  *(bf16x8*)(dst + i * 8) = o;
}

__global__ void cast_ehs_kernel(const float* __restrict__ src, unsigned short* __restrict__ dst) {
  int idx = blockIdx.x * 256 + threadIdx.x;  // 768*96 = 73728 threads
  int r = idx / 96, c = (idx % 96) * 8;
  bf16x8 o;
  if (r < 672) {
    const float4* s = (const float4*)(src + (long)r * 768 + c);
    float4 a = s[0], b = s[1];
    o[0] = (short)f2bf(a.x); o[1] = (short)f2bf(a.y); o[2] = (short)f2bf(a.z); o[3] = (short)f2bf(a.w);
    o[4] = (short)f2bf(b.x); o[5] = (short)f2bf(b.y); o[6] = (short)f2bf(b.z); o[7] = (short)f2bf(b.w);
  } else {
    #pragma unroll
    for (int t = 0; t < 8; t++) o[t] = 0;
  }
  *(bf16x8*)(dst + (long)r * 768 + c) = o;
}

// ---------------- GEMM: C[m,n] = sum_k A[m,k]*B[n,k] + bias[n] ----------------
// 128x128 tile, BK=32, 4 waves (2x2), mfma_f32_16x16x32_bf16, m97-style.
// SWZ=1: 1D grid of exactly 4096 blocks (M_TILES=256, N_TILES=16);
//        XCD-chunked remap (bijective, 4096%8==0) + 16x16 supertile so the
//        concurrently-resident blocks share 16 A-panels + all of B (L3-fit).
template <int OUTF, int SWZ>
__global__ __launch_bounds__(256, 2)
void gemm_bt(const unsigned short* __restrict__ A, const unsigned short* __restrict__ B,
             const float* __restrict__ bias, void* __restrict__ C,
             int M, int N, int K, int M_valid) {
  __shared__ unsigned short As[128 * 32];
  __shared__ unsigned short Bs[128 * 32];
  int mt, nt;
  if (SWZ) {
    int orig = blockIdx.x;
    int wgid = (orig & 7) * 512 + (orig >> 3);   // XCD chunked remap, nwg=4096
    int st = wgid >> 8, w = wgid & 255;          // 16 supertiles of 256 blocks
    mt = st * 16 + (w & 15);                     // 16 M-tiles per supertile
    nt = w >> 4;                                 // all 16 N-tiles
  } else {
    mt = blockIdx.x; nt = blockIdx.y;
  }
  const int m0 = mt * 128;
  const int n0 = nt * 128;
  const int tid = threadIdx.x;
  const int wave = tid >> 6;
  const int lane = tid & 63;
  const int wr = wave >> 1, wc = wave & 1;
  const int lrow = lane >> 2, lcol = lane & 3;

  f32x4 acc[4][4];
  #pragma unroll
  for (int i = 0; i < 4; i++)
    #pragma unroll
    for (int j = 0; j < 4; j++) acc[i][j] = (f32x4){0.f, 0.f, 0.f, 0.f};

  const unsigned short* gA = A + (long)(m0 + wave * 32 + lrow) * K + lcol * 8;
  const unsigned short* gB = B + (long)(n0 + wave * 32 + lrow) * K + lcol * 8;
  unsigned short* lA0 = &As[wave * 1024];
  unsigned short* lA1 = &As[wave * 1024 + 512];
  unsigned short* lB0 = &Bs[wave * 1024];
  unsigned short* lB1 = &Bs[wave * 1024 + 512];

  for (int k0 = 0; k0 < K; k0 += 32) {
    stage16(gA + k0, lA0, lane);
    stage16(gA + k0 + 16 * K, lA1, lane);
    stage16(gB + k0, lB0, lane);
    stage16(gB + k0 + 16 * K, lB1, lane);
    __syncthreads();
    bf16x8 af[4], bfr[4];
    const int kq = (lane >> 4) * 8;
    const int rr = lane & 15;
    #pragma unroll
    for (int mi = 0; mi < 4; mi++) af[mi] = *(const bf16x8*)&As[(wr * 64 + mi * 16 + rr) * 32 + kq];
    #pragma unroll
    for (int ni = 0; ni < 4; ni++) bfr[ni] = *(const bf16x8*)&Bs[(wc * 64 + ni * 16 + rr) * 32 + kq];
    #pragma unroll
    for (int mi = 0; mi < 4; mi++)
      #pragma unroll
      for (int ni = 0; ni < 4; ni++)
        acc[mi][ni] = __builtin_amdgcn_mfma_f32_16x16x32_bf16(af[mi], bfr[ni], acc[mi][ni], 0, 0, 0);
    __syncthreads();
  }

  const int colL = lane & 15, rq = (lane >> 4) * 4;
  #pragma unroll
  for (int mi = 0; mi < 4; mi++) {
    #pragma unroll
    for (int ni = 0; ni < 4; ni++) {
      int col = n0 + wc * 64 + ni * 16 + colL;
      float bv = bias[col];
      #pragma unroll
      for (int r = 0; r < 4; r++) {
        int row = m0 + wr * 64 + mi * 16 + rq + r;
        if (row < M_valid) {
          float v = acc[mi][ni][r] + bv;
          if (OUTF) ((float*)C)[(long)row * N + col] = v;
          else      ((unsigned short*)C)[(long)row * N + col] = f2bf(v);
        }
      }
    }
  }
}

// ---------------- RoPE on K (in place, fixed positions 2 / 22) ----------------
__global__ void rope_k_kernel(unsigned short* __restrict__ kv) {
  int r = blockIdx.x;           // 0..671 (row = b*32 + a)
  int c = threadIdx.x * 8;      // only k half: cols 0..2047
  float pos = ((r & 31) < 16) ? 2.0f : 22.0f;
  unsigned short* p = kv + (long)r * 4096 + c;
  bf16x8 v = *(const bf16x8*)p;
  int jb = (c & 63) >> 1;
  bf16x8 o;
  #pragma unroll
  for (int t = 0; t < 4; t++) {
    float invf = __expf(-(float)(jb + t) * LN10000_32);
    float f = pos * invf;
    float s_, c_;
    sincosf(f, &s_, &c_);
    float x1 = bf2f((unsigned short)v[2 * t]);
    float x2 = bf2f((unsigned short)v[2 * t + 1]);
    o[2 * t]     = (short)f2bf(x1 * c_ - x2 * s_);
    o[2 * t + 1] = (short)f2bf(x1 * s_ + x2 * c_);
  }
  *(bf16x8*)p = o;
}

// ---------------- attention: RoPE(Q) fused + 32 keys, VALU, in place ----------
__global__ __launch_bounds__(256)
void attn_kernel(const unsigned short* __restrict__ kv, unsigned short* __restrict__ q,
                 const float2* __restrict__ tab) {
  __shared__ float Ks[2048];
  __shared__ float Vs[2048];
  const int bh = blockIdx.y;
  const int b = bh >> 5, h = bh & 31;
  const int tid = threadIdx.x;
  for (int i = tid; i < 2048; i += 256) {
    int a = i >> 6, d = i & 63;
    long off = ((long)(b * 32 + a)) * 4096 + h * 64 + d;
    Ks[i] = bf2f(kv[off]);
    Vs[i] = bf2f(kv[off + 2048]);
  }
  __syncthreads();
  int s = blockIdx.x * 256 + tid;
  if (s >= 1560) return;
  const long row = (long)b * 1560 + s;
  unsigned short* qp = q + row * 2048 + h * 64;
  float qr[64];
  #pragma unroll
  for (int i = 0; i < 8; i++) {
    bf16x8 v = *(const bf16x8*)(qp + i * 8);
    #pragma unroll
    for (int j = 0; j < 8; j++) qr[i * 8 + j] = bf2f((unsigned short)v[j]);
  }
  // fused RoPE(Q): pairs (2j, 2j+1) within the 64-d head, table-driven
  const float2* trow = tab + row * 32;
  #pragma unroll
  for (int j = 0; j < 32; j++) {
    float2 cs = trow[j];
    float x1 = qr[2 * j], x2 = qr[2 * j + 1];
    qr[2 * j]     = x1 * cs.x - x2 * cs.y;
    qr[2 * j + 1] = x1 * cs.y + x2 * cs.x;
  }
  float sc[32];
  float mx = -3.4e38f;
  #pragma unroll
  for (int a = 0; a < 32; a++) {
    float acc = 0.f;
    #pragma unroll
    for (int d = 0; d < 64; d++) acc = fmaf(qr[d], Ks[a * 64 + d], acc);
    acc *= 0.125f;
    sc[a] = acc;
    mx = fmaxf(mx, acc);
  }
  float sum = 0.f;
  #pragma unroll
  for (int a = 0; a < 32; a++) { float e = __expf(sc[a] - mx); sc[a] = e; sum += e; }
  float inv = 1.f / sum;
  float outr[64];
  #pragma unroll
  for (int d = 0; d < 64; d++) outr[d] = 0.f;
  #pragma unroll
  for (int a = 0; a < 32; a++) {
    float p = sc[a] * inv;
    #pragma unroll
    for (int d = 0; d < 64; d++) outr[d] = fmaf(p, Vs[a * 64 + d], outr[d]);
  }
  #pragma unroll
  for (int i = 0; i < 8; i++) {
    bf16x8 v;
    #pragma unroll
    for (int j = 0; j < 8; j++) v[j] = (short)f2bf(outr[i * 8 + j]);
    *(bf16x8*)(qp + i * 8) = v;
  }
}

// ---------------- launch ------------------------------------------------------
extern "C" void kernel_launch(void* const* d_in, const int* in_sizes, int n_in,
                              void* d_out, int out_size, void* d_ws, size_t ws_size,
                              hipStream_t stream) {
  const float* x      = (const float*)d_in[0];
  const float* ehs    = (const float*)d_in[1];
  const float* xmap   = (const float*)d_in[2];
  const float* q_w    = (const float*)d_in[3];
  const float* q_b    = (const float*)d_in[4];
  const float* kv_w   = (const float*)d_in[5];
  const float* kv_b   = (const float*)d_in[6];
  const float* proj_w = (const float*)d_in[7];
  const float* proj_b = (const float*)d_in[8];
  float* out = (float*)d_out;

  // ws layout (bytes)
  char* ws = (char*)d_ws;
  float*          mm    = (float*)(ws + 0);            // 4 floats
  float2*         tab   = (float2*)(ws + 256);         // 32768*32*8 = 8,388,608
  unsigned short* qbuf  = (unsigned short*)(ws + 8388864);    // 32768*2048*2 = 134,217,728
  unsigned short* kvbuf = (unsigned short*)(ws + 142606592);  // 768*4096*2   = 6,291,456
  unsigned short* ehsb  = (unsigned short*)(ws + 148898048);  // 768*768*2    = 1,179,648
  unsigned short* qwb   = (unsigned short*)(ws + 150077696);  // 2048*2048*2  = 8,388,608
  unsigned short* kvwb  = (unsigned short*)(ws + 158466304);  // 4096*768*2   = 6,291,456
  unsigned short* pwb   = (unsigned short*)(ws + 164757760);  // 2048*2048*2  = 8,388,608
  unsigned short* xb    = (unsigned short*)d_out;             // x as bf16 (dead before final GEMM)

  minmax_kernel<<<1, 256, 0, stream>>>(xmap, mm);
  pos_table_kernel<<<128, 256, 0, stream>>>(xmap, mm, tab);
  cast_x_kernel<<<32768, 256, 0, stream>>>(x, xb);
  cast_flat_kernel<<<2048, 256, 0, stream>>>(q_w, qwb, 524288);
  cast_flat_kernel<<<1536, 256, 0, stream>>>(kv_w, kvwb, 393216);
  cast_flat_kernel<<<2048, 256, 0, stream>>>(proj_w, pwb, 524288);
  cast_ehs_kernel<<<288, 256, 0, stream>>>(ehs, ehsb);

  gemm_bt<0, 1><<<4096, 256, 0, stream>>>(xb, qwb, q_b, qbuf, 32768, 2048, 2048, 32768);
  gemm_bt<0, 0><<<dim3(6, 32), 256, 0, stream>>>(ehsb, kvwb, kv_b, kvbuf, 768, 4096, 768, 768);

  rope_k_kernel<<<672, 256, 0, stream>>>(kvbuf);

  attn_kernel<<<dim3(7, 672), 256, 0, stream>>>(kvbuf, qbuf, tab);

  gemm_bt<1, 1><<<4096, 256, 0, stream>>>(qbuf, pwb, proj_b, out, 32768, 2048, 2048, 32760);
}

// Round 3
// 1084.148 us; speedup vs baseline: 1.0776x; 1.0384x over previous
//
#include <hip/hip_runtime.h>

typedef short bf16x8 __attribute__((ext_vector_type(8)));
typedef float f32x4 __attribute__((ext_vector_type(4)));

#define LN10000_32 0.2878231406211853f  // ln(10000)/32

__device__ __forceinline__ unsigned short f2bf(float f) {
  union { float f; unsigned int u; } v; v.f = f;
  unsigned int r = v.u + 0x7fffu + ((v.u >> 16) & 1u);
  return (unsigned short)(r >> 16);
}
__device__ __forceinline__ float bf2f(unsigned short h) {
  union { unsigned int u; float f; } v; v.u = ((unsigned int)h) << 16;
  return v.f;
}

__device__ __forceinline__ void stage16(const unsigned short* g, unsigned short* lds_base, int lane) {
#if __has_builtin(__builtin_amdgcn_global_load_lds)
  (void)lane;
  __builtin_amdgcn_global_load_lds((const __attribute__((address_space(1))) void*)g,
                                   (__attribute__((address_space(3))) void*)lds_base,
                                   16, 0, 0);
#else
  *(bf16x8*)((char*)lds_base + lane * 16) = *(const bf16x8*)g;
#endif
}

// ---------------- min/max of the two x_ref_attn_map rows ---------------------
__global__ void minmax_kernel(const float* __restrict__ xmap, float* __restrict__ mm) {
  __shared__ float red[4][256];
  int t = threadIdx.x;
  float mn0 = 3.4e38f, mx0 = -3.4e38f, mn1 = 3.4e38f, mx1 = -3.4e38f;
  for (int i = t; i < 32760; i += 256) {
    float a = xmap[i];          mn0 = fminf(mn0, a); mx0 = fmaxf(mx0, a);
    float b = xmap[32760 + i];  mn1 = fminf(mn1, b); mx1 = fmaxf(mx1, b);
  }
  red[0][t] = mn0; red[1][t] = mx0; red[2][t] = mn1; red[3][t] = mx1;
  __syncthreads();
  for (int s = 128; s > 0; s >>= 1) {
    if (t < s) {
      red[0][t] = fminf(red[0][t], red[0][t + s]);
      red[1][t] = fmaxf(red[1][t], red[1][t + s]);
      red[2][t] = fminf(red[2][t], red[2][t + s]);
      red[3][t] = fmaxf(red[3][t], red[3][t + s]);
    }
    __syncthreads();
  }
  if (t == 0) { mm[0] = red[0][0]; mm[1] = red[1][0]; mm[2] = red[2][0]; mm[3] = red[3][0]; }
}

// ---------------- normalized position -> cos/sin table (32760 x 32) ----------
__global__ void pos_table_kernel(const float* __restrict__ xmap, const float* __restrict__ mm,
                                 float2* __restrict__ tab) {
  int n = blockIdx.x * 256 + threadIdx.x;
  if (n >= 32760) return;
  float m0 = xmap[n], m1 = xmap[32760 + n];
  float pos;
  if (m1 > m0) pos = (m1 - mm[2]) / (mm[3] - mm[2] + 1e-8f) * 4.0f + 20.0f;
  else         pos = (m0 - mm[0]) / (mm[1] - mm[0] + 1e-8f) * 4.0f;
  #pragma unroll
  for (int j = 0; j < 32; j++) {
    float invf = __expf(-(float)j * LN10000_32);
    float f = pos * invf;
    float s, c;
    sincosf(f, &s, &c);
    tab[(long)n * 32 + j] = make_float2(c, s);
  }
}

// ---------------- casts -------------------------------------------------------
__global__ void cast_x_kernel(const float* __restrict__ src, unsigned short* __restrict__ dst) {
  int r = blockIdx.x;
  int c = threadIdx.x * 8;
  bf16x8 o;
  if (r < 32760) {
    const float4* s = (const float4*)(src + (long)r * 2048 + c);
    float4 a = s[0], b = s[1];
    o[0] = (short)f2bf(a.x); o[1] = (short)f2bf(a.y); o[2] = (short)f2bf(a.z); o[3] = (short)f2bf(a.w);
    o[4] = (short)f2bf(b.x); o[5] = (short)f2bf(b.y); o[6] = (short)f2bf(b.z); o[7] = (short)f2bf(b.w);
  } else {
    #pragma unroll
    for (int t = 0; t < 8; t++) o[t] = 0;
  }
  *(bf16x8*)(dst + (long)r * 2048 + c) = o;
}

__global__ void cast_flat_kernel(const float* __restrict__ src, unsigned short* __restrict__ dst, long n8) {
  long i = (long)blockIdx.x * 256 + threadIdx.x;
  if (i >= n8) return;
  const float4* s = (const float4*)(src + i * 8);
  float4 a = s[0], b = s[1];
  bf16x8 o;
  o[0] = (short)f2bf(a.x); o[1] = (short)f2bf(a.y); o[2] = (short)f2bf(a.z); o[3] = (short)f2bf(a.w);
  o[4] = (short)f2bf(b.x); o[5] = (short)f2bf(b.y); o[6] = (short)f2bf(b.z); o[7] = (short)f2bf(b.w);
  *(bf16x8*)(dst + i * 8) = o;
}

__global__ void cast_ehs_kernel(const float* __restrict__ src, unsigned short* __restrict__ dst) {
  int idx = blockIdx.x * 256 + threadIdx.x;
  int r = idx / 96, c = (idx % 96) * 8;
  bf16x8 o;
  if (r < 672) {
    const float4* s = (const float4*)(src + (long)r * 768 + c);
    float4 a = s[0], b = s[1];
    o[0] = (short)f2bf(a.x); o[1] = (short)f2bf(a.y); o[2] = (short)f2bf(a.z); o[3] = (short)f2bf(a.w);
    o[4] = (short)f2bf(b.x); o[5] = (short)f2bf(b.y); o[6] = (short)f2bf(b.z); o[7] = (short)f2bf(b.w);
  } else {
    #pragma unroll
    for (int t = 0; t < 8; t++) o[t] = 0;
  }
  *(bf16x8*)(dst + (long)r * 768 + c) = o;
}

// ---------------- small GEMM (128x128 m97-style) for KV projection -----------
template <int OUTF, int SWZ>
__global__ __launch_bounds__(256, 2)
void gemm_bt(const unsigned short* __restrict__ A, const unsigned short* __restrict__ B,
             const float* __restrict__ bias, void* __restrict__ C,
             int M, int N, int K, int M_valid) {
  __shared__ unsigned short As[128 * 32];
  __shared__ unsigned short Bs[128 * 32];
  int mt, nt;
  if (SWZ) {
    int orig = blockIdx.x;
    int wgid = (orig & 7) * 512 + (orig >> 3);
    int st = wgid >> 8, w = wgid & 255;
    mt = st * 16 + (w & 15);
    nt = w >> 4;
  } else {
    mt = blockIdx.x; nt = blockIdx.y;
  }
  const int m0 = mt * 128;
  const int n0 = nt * 128;
  const int tid = threadIdx.x;
  const int wave = tid >> 6;
  const int lane = tid & 63;
  const int wr = wave >> 1, wc = wave & 1;
  const int lrow = lane >> 2, lcol = lane & 3;

  f32x4 acc[4][4];
  #pragma unroll
  for (int i = 0; i < 4; i++)
    #pragma unroll
    for (int j = 0; j < 4; j++) acc[i][j] = (f32x4){0.f, 0.f, 0.f, 0.f};

  const unsigned short* gA = A + (long)(m0 + wave * 32 + lrow) * K + lcol * 8;
  const unsigned short* gB = B + (long)(n0 + wave * 32 + lrow) * K + lcol * 8;
  unsigned short* lA0 = &As[wave * 1024];
  unsigned short* lA1 = &As[wave * 1024 + 512];
  unsigned short* lB0 = &Bs[wave * 1024];
  unsigned short* lB1 = &Bs[wave * 1024 + 512];

  for (int k0 = 0; k0 < K; k0 += 32) {
    stage16(gA + k0, lA0, lane);
    stage16(gA + k0 + 16 * K, lA1, lane);
    stage16(gB + k0, lB0, lane);
    stage16(gB + k0 + 16 * K, lB1, lane);
    __syncthreads();
    bf16x8 af[4], bfr[4];
    const int kq = (lane >> 4) * 8;
    const int rr = lane & 15;
    #pragma unroll
    for (int mi = 0; mi < 4; mi++) af[mi] = *(const bf16x8*)&As[(wr * 64 + mi * 16 + rr) * 32 + kq];
    #pragma unroll
    for (int ni = 0; ni < 4; ni++) bfr[ni] = *(const bf16x8*)&Bs[(wc * 64 + ni * 16 + rr) * 32 + kq];
    #pragma unroll
    for (int mi = 0; mi < 4; mi++)
      #pragma unroll
      for (int ni = 0; ni < 4; ni++)
        acc[mi][ni] = __builtin_amdgcn_mfma_f32_16x16x32_bf16(af[mi], bfr[ni], acc[mi][ni], 0, 0, 0);
    __syncthreads();
  }

  const int colL = lane & 15, rq = (lane >> 4) * 4;
  #pragma unroll
  for (int mi = 0; mi < 4; mi++) {
    #pragma unroll
    for (int ni = 0; ni < 4; ni++) {
      int col = n0 + wc * 64 + ni * 16 + colL;
      float bv = bias[col];
      #pragma unroll
      for (int r = 0; r < 4; r++) {
        int row = m0 + wr * 64 + mi * 16 + rq + r;
        if (row < M_valid) {
          float v = acc[mi][ni][r] + bv;
          if (OUTF) ((float*)C)[(long)row * N + col] = v;
          else      ((unsigned short*)C)[(long)row * N + col] = f2bf(v);
        }
      }
    }
  }
}

// ---------------- big GEMM: 256x256 tile, BK=32, ring-4 LDS, phased ----------
// C[m,n] = sum_k A[m,k]*B[n,k] + bias[n].  8 waves (2M x 4N), per-wave 128x64.
// Ring of 4 subtile slots (A 16KB + B 16KB each = 128 KiB LDS); staging runs 3
// subtiles ahead of compute (writes slot (t+3)&3 = (t-1)&3, dead since end of
// t-1). Counted vmcnt(8) at subtile boundary: outstanding <= {t+2,t+3} = 8
// loads, so t+1 is guaranteed landed. LDS block-swizzle blk ^= (row>>1)&3
// (inverse applied on the per-lane global source; linear global_load_lds dest).
template <int OUTF>
__global__ __launch_bounds__(512, 2)
void gemm256(const unsigned short* __restrict__ A, const unsigned short* __restrict__ B,
             const float* __restrict__ bias, void* __restrict__ C,
             int K, int N, int M_valid) {
  extern __shared__ __align__(16) unsigned short lds_us[];  // 4*16384 ushorts
  const int NT = K >> 5;
  const int orig = blockIdx.x;
  const int cpx = (int)gridDim.x >> 3;
  const int wgid = (orig & 7) * cpx + (orig >> 3);
  const int nt = wgid & 7;            // 8 N-tiles (N=2048)
  const int mt = wgid >> 3;
  const int m0 = mt << 8, n0 = nt << 8;
  const int tid = threadIdx.x;
  const int w = tid >> 6, l = tid & 63;
  const int wr = w >> 2, wc = w & 3;
  const int i = l & 15, kq = l >> 4;

  // staging: lane l of wave w covers row w*16 + (l>>2) (+r*128), 16B-block l&3.
  // source pre-swizzle: global block = (l&3) ^ ((l>>3)&3)  [= (row>>1)&3]
  const int rl = w * 16 + (l >> 2);
  const int blkg = ((l & 3) ^ ((l >> 3) & 3)) * 8;
  const unsigned short* pA = A + (long)(m0 + rl) * K + blkg;
  const unsigned short* pB = B + (long)(n0 + rl) * K + blkg;
  unsigned short* stW = lds_us + w * 512;  // wave-uniform dest base (+slot, +round)

  // fragment read: row = base+ i, k-block kq; swizzled block = kq ^ ((i>>1)&3)
  const int core = i * 32 + ((kq ^ ((i >> 1) & 3)) << 3);
  const unsigned short* fA = lds_us + wr * 4096 + core;          // + slot*16384 + mi*512
  const unsigned short* fB = lds_us + 8192 + wc * 2048 + core;   // + slot*16384 + ni*512

  f32x4 acc[8][4];
  #pragma unroll
  for (int a = 0; a < 8; a++)
    #pragma unroll
    for (int b = 0; b < 4; b++) acc[a][b] = (f32x4){0.f, 0.f, 0.f, 0.f};

#define STAGE_A(s) { \
    const unsigned short* g_ = pA + (s) * 32; \
    unsigned short* d_ = stW + ((s) & 3) * 16384; \
    stage16(g_, d_, l); \
    stage16(g_ + (long)128 * K, d_ + 4096, l); }
#define STAGE_B(s) { \
    const unsigned short* g_ = pB + (s) * 32; \
    unsigned short* d_ = stW + ((s) & 3) * 16384 + 8192; \
    stage16(g_, d_, l); \
    stage16(g_ + (long)128 * K, d_ + 4096, l); }

  // prologue: stage subtiles 0,1,2 (12 loads); wait until subtile 0 landed.
  STAGE_A(0); STAGE_B(0);
  STAGE_A(1); STAGE_B(1);
  STAGE_A(2); STAGE_B(2);
  asm volatile("s_waitcnt vmcnt(8)" ::: "memory");
  __builtin_amdgcn_s_barrier();

  for (int t = 0; t < NT; ++t) {
    const int slot = (t & 3) * 16384;
    const unsigned short* sA = fA + slot;
    const unsigned short* sB = fB + slot;
    // ---- phase 1: read B0-3, A0-3; stage A of t+3; MFMA quadrant (m0-3) ----
    bf16x8 b0 = *(const bf16x8*)(sB);
    bf16x8 b1 = *(const bf16x8*)(sB + 512);
    bf16x8 b2 = *(const bf16x8*)(sB + 1024);
    bf16x8 b3 = *(const bf16x8*)(sB + 1536);
    bf16x8 a0 = *(const bf16x8*)(sA);
    bf16x8 a1 = *(const bf16x8*)(sA + 512);
    bf16x8 a2 = *(const bf16x8*)(sA + 1024);
    bf16x8 a3 = *(const bf16x8*)(sA + 1536);
    if (t + 3 < NT) STAGE_A(t + 3);
    __builtin_amdgcn_s_barrier();
    asm volatile("s_waitcnt lgkmcnt(0)" ::: "memory");
    __builtin_amdgcn_sched_barrier(0);
    __builtin_amdgcn_s_setprio(1);
    acc[0][0] = __builtin_amdgcn_mfma_f32_16x16x32_bf16(a0, b0, acc[0][0], 0, 0, 0);
    acc[0][1] = __builtin_amdgcn_mfma_f32_16x16x32_bf16(a0, b1, acc[0][1], 0, 0, 0);
    acc[0][2] = __builtin_amdgcn_mfma_f32_16x16x32_bf16(a0, b2, acc[0][2], 0, 0, 0);
    acc[0][3] = __builtin_amdgcn_mfma_f32_16x16x32_bf16(a0, b3, acc[0][3], 0, 0, 0);
    acc[1][0] = __builtin_amdgcn_mfma_f32_16x16x32_bf16(a1, b0, acc[1][0], 0, 0, 0);
    acc[1][1] = __builtin_amdgcn_mfma_f32_16x16x32_bf16(a1, b1, acc[1][1], 0, 0, 0);
    acc[1][2] = __builtin_amdgcn_mfma_f32_16x16x32_bf16(a1, b2, acc[1][2], 0, 0, 0);
    acc[1][3] = __builtin_amdgcn_mfma_f32_16x16x32_bf16(a1, b3, acc[1][3], 0, 0, 0);
    acc[2][0] = __builtin_amdgcn_mfma_f32_16x16x32_bf16(a2, b0, acc[2][0], 0, 0, 0);
    acc[2][1] = __builtin_amdgcn_mfma_f32_16x16x32_bf16(a2, b1, acc[2][1], 0, 0, 0);
    acc[2][2] = __builtin_amdgcn_mfma_f32_16x16x32_bf16(a2, b2, acc[2][2], 0, 0, 0);
    acc[2][3] = __builtin_amdgcn_mfma_f32_16x16x32_bf16(a2, b3, acc[2][3], 0, 0, 0);
    acc[3][0] = __builtin_amdgcn_mfma_f32_16x16x32_bf16(a3, b0, acc[3][0], 0, 0, 0);
    acc[3][1] = __builtin_amdgcn_mfma_f32_16x16x32_bf16(a3, b1, acc[3][1], 0, 0, 0);
    acc[3][2] = __builtin_amdgcn_mfma_f32_16x16x32_bf16(a3, b2, acc[3][2], 0, 0, 0);
    acc[3][3] = __builtin_amdgcn_mfma_f32_16x16x32_bf16(a3, b3, acc[3][3], 0, 0, 0);
    __builtin_amdgcn_s_setprio(0);
    __builtin_amdgcn_s_barrier();
    // ---- phase 2: read A4-7; stage B of t+3; vmcnt(8); MFMA quadrant (m4-7) -
    bf16x8 a4 = *(const bf16x8*)(sA + 2048);
    bf16x8 a5 = *(const bf16x8*)(sA + 2560);
    bf16x8 a6 = *(const bf16x8*)(sA + 3072);
    bf16x8 a7 = *(const bf16x8*)(sA + 3584);
    if (t + 3 < NT) STAGE_B(t + 3);
    asm volatile("s_waitcnt vmcnt(8)" ::: "memory");
    __builtin_amdgcn_s_barrier();
    asm volatile("s_waitcnt lgkmcnt(0)" ::: "memory");
    __builtin_amdgcn_sched_barrier(0);
    __builtin_amdgcn_s_setprio(1);
    acc[4][0] = __builtin_amdgcn_mfma_f32_16x16x32_bf16(a4, b0, acc[4][0], 0, 0, 0);
    acc[4][1] = __builtin_amdgcn_mfma_f32_16x16x32_bf16(a4, b1, acc[4][1], 0, 0, 0);
    acc[4][2] = __builtin_amdgcn_mfma_f32_16x16x32_bf16(a4, b2, acc[4][2], 0, 0, 0);
    acc[4][3] = __builtin_amdgcn_mfma_f32_16x16x32_bf16(a4, b3, acc[4][3], 0, 0, 0);
    acc[5][0] = __builtin_amdgcn_mfma_f32_16x16x32_bf16(a5, b0, acc[5][0], 0, 0, 0);
    acc[5][1] = __builtin_amdgcn_mfma_f32_16x16x32_bf16(a5, b1, acc[5][1], 0, 0, 0);
    acc[5][2] = __builtin_amdgcn_mfma_f32_16x16x32_bf16(a5, b2, acc[5][2], 0, 0, 0);
    acc[5][3] = __builtin_amdgcn_mfma_f32_16x16x32_bf16(a5, b3, acc[5][3], 0, 0, 0);
    acc[6][0] = __builtin_amdgcn_mfma_f32_16x16x32_bf16(a6, b0, acc[6][0], 0, 0, 0);
    acc[6][1] = __builtin_amdgcn_mfma_f32_16x16x32_bf16(a6, b1, acc[6][1], 0, 0, 0);
    acc[6][2] = __builtin_amdgcn_mfma_f32_16x16x32_bf16(a6, b2, acc[6][2], 0, 0, 0);
    acc[6][3] = __builtin_amdgcn_mfma_f32_16x16x32_bf16(a6, b3, acc[6][3], 0, 0, 0);
    acc[7][0] = __builtin_amdgcn_mfma_f32_16x16x32_bf16(a7, b0, acc[7][0], 0, 0, 0);
    acc[7][1] = __builtin_amdgcn_mfma_f32_16x16x32_bf16(a7, b1, acc[7][1], 0, 0, 0);
    acc[7][2] = __builtin_amdgcn_mfma_f32_16x16x32_bf16(a7, b2, acc[7][2], 0, 0, 0);
    acc[7][3] = __builtin_amdgcn_mfma_f32_16x16x32_bf16(a7, b3, acc[7][3], 0, 0, 0);
    __builtin_amdgcn_s_setprio(0);
    __builtin_amdgcn_s_barrier();
  }
#undef STAGE_A
#undef STAGE_B

  // epilogue
  #pragma unroll
  for (int ni = 0; ni < 4; ni++) {
    int col = n0 + wc * 64 + ni * 16 + i;
    float bv = bias[col];
    #pragma unroll
    for (int mi = 0; mi < 8; mi++) {
      int rowb = m0 + wr * 128 + mi * 16 + kq * 4;
      #pragma unroll
      for (int r = 0; r < 4; r++) {
        int row = rowb + r;
        if (row < M_valid) {
          float v = acc[mi][ni][r] + bv;
          if (OUTF) ((float*)C)[(long)row * N + col] = v;
          else      ((unsigned short*)C)[(long)row * N + col] = f2bf(v);
        }
      }
    }
  }
}

// ---------------- RoPE on K (in place, fixed positions 2 / 22) ----------------
__global__ void rope_k_kernel(unsigned short* __restrict__ kv) {
  int r = blockIdx.x;
  int c = threadIdx.x * 8;
  float pos = ((r & 31) < 16) ? 2.0f : 22.0f;
  unsigned short* p = kv + (long)r * 4096 + c;
  bf16x8 v = *(const bf16x8*)p;
  int jb = (c & 63) >> 1;
  bf16x8 o;
  #pragma unroll
  for (int t = 0; t < 4; t++) {
    float invf = __expf(-(float)(jb + t) * LN10000_32);
    float f = pos * invf;
    float s_, c_;
    sincosf(f, &s_, &c_);
    float x1 = bf2f((unsigned short)v[2 * t]);
    float x2 = bf2f((unsigned short)v[2 * t + 1]);
    o[2 * t]     = (short)f2bf(x1 * c_ - x2 * s_);
    o[2 * t + 1] = (short)f2bf(x1 * s_ + x2 * c_);
  }
  *(bf16x8*)p = o;
}

// ---------------- attention: RoPE(Q) fused + 32 keys, VALU, in place ----------
__global__ __launch_bounds__(256)
void attn_kernel(const unsigned short* __restrict__ kv, unsigned short* __restrict__ q,
                 const float2* __restrict__ tab) {
  __shared__ float Ks[2048];
  __shared__ float Vs[2048];
  const int bh = blockIdx.y;
  const int b = bh >> 5, h = bh & 31;
  const int tid = threadIdx.x;
  for (int i = tid; i < 2048; i += 256) {
    int a = i >> 6, d = i & 63;
    long off = ((long)(b * 32 + a)) * 4096 + h * 64 + d;
    Ks[i] = bf2f(kv[off]);
    Vs[i] = bf2f(kv[off + 2048]);
  }
  __syncthreads();
  int s = blockIdx.x * 256 + tid;
  if (s >= 1560) return;
  const long row = (long)b * 1560 + s;
  unsigned short* qp = q + row * 2048 + h * 64;
  float qr[64];
  #pragma unroll
  for (int i = 0; i < 8; i++) {
    bf16x8 v = *(const bf16x8*)(qp + i * 8);
    #pragma unroll
    for (int j = 0; j < 8; j++) qr[i * 8 + j] = bf2f((unsigned short)v[j]);
  }
  const float2* trow = tab + row * 32;
  #pragma unroll
  for (int j = 0; j < 32; j++) {
    float2 cs = trow[j];
    float x1 = qr[2 * j], x2 = qr[2 * j + 1];
    qr[2 * j]     = x1 * cs.x - x2 * cs.y;
    qr[2 * j + 1] = x1 * cs.y + x2 * cs.x;
  }
  float sc[32];
  float mx = -3.4e38f;
  #pragma unroll
  for (int a = 0; a < 32; a++) {
    float acc = 0.f;
    #pragma unroll
    for (int d = 0; d < 64; d++) acc = fmaf(qr[d], Ks[a * 64 + d], acc);
    acc *= 0.125f;
    sc[a] = acc;
    mx = fmaxf(mx, acc);
  }
  float sum = 0.f;
  #pragma unroll
  for (int a = 0; a < 32; a++) { float e = __expf(sc[a] - mx); sc[a] = e; sum += e; }
  float inv = 1.f / sum;
  float outr[64];
  #pragma unroll
  for (int d = 0; d < 64; d++) outr[d] = 0.f;
  #pragma unroll
  for (int a = 0; a < 32; a++) {
    float p = sc[a] * inv;
    #pragma unroll
    for (int d = 0; d < 64; d++) outr[d] = fmaf(p, Vs[a * 64 + d], outr[d]);
  }
  #pragma unroll
  for (int i = 0; i < 8; i++) {
    bf16x8 v;
    #pragma unroll
    for (int j = 0; j < 8; j++) v[j] = (short)f2bf(outr[i * 8 + j]);
    *(bf16x8*)(qp + i * 8) = v;
  }
}

// ---------------- launch ------------------------------------------------------
extern "C" void kernel_launch(void* const* d_in, const int* in_sizes, int n_in,
                              void* d_out, int out_size, void* d_ws, size_t ws_size,
                              hipStream_t stream) {
  const float* x      = (const float*)d_in[0];
  const float* ehs    = (const float*)d_in[1];
  const float* xmap   = (const float*)d_in[2];
  const float* q_w    = (const float*)d_in[3];
  const float* q_b    = (const float*)d_in[4];
  const float* kv_w   = (const float*)d_in[5];
  const float* kv_b   = (const float*)d_in[6];
  const float* proj_w = (const float*)d_in[7];
  const float* proj_b = (const float*)d_in[8];
  float* out = (float*)d_out;

  char* ws = (char*)d_ws;
  float*          mm    = (float*)(ws + 0);
  float2*         tab   = (float2*)(ws + 256);
  unsigned short* qbuf  = (unsigned short*)(ws + 8388864);
  unsigned short* kvbuf = (unsigned short*)(ws + 142606592);
  unsigned short* ehsb  = (unsigned short*)(ws + 148898048);
  unsigned short* qwb   = (unsigned short*)(ws + 150077696);
  unsigned short* kvwb  = (unsigned short*)(ws + 158466304);
  unsigned short* pwb   = (unsigned short*)(ws + 164757760);
  unsigned short* xb    = (unsigned short*)d_out;

  // allow 128 KiB dynamic LDS for the big GEMM (idempotent, capture-safe)
  (void)hipFuncSetAttribute((const void*)gemm256<0>, hipFuncAttributeMaxDynamicSharedMemorySize, 131072);
  (void)hipFuncSetAttribute((const void*)gemm256<1>, hipFuncAttributeMaxDynamicSharedMemorySize, 131072);

  minmax_kernel<<<1, 256, 0, stream>>>(xmap, mm);
  pos_table_kernel<<<128, 256, 0, stream>>>(xmap, mm, tab);
  cast_x_kernel<<<32768, 256, 0, stream>>>(x, xb);
  cast_flat_kernel<<<2048, 256, 0, stream>>>(q_w, qwb, 524288);
  cast_flat_kernel<<<1536, 256, 0, stream>>>(kv_w, kvwb, 393216);
  cast_flat_kernel<<<2048, 256, 0, stream>>>(proj_w, pwb, 524288);
  cast_ehs_kernel<<<288, 256, 0, stream>>>(ehs, ehsb);

  gemm256<0><<<1024, 512, 131072, stream>>>(xb, qwb, q_b, qbuf, 2048, 2048, 32768);
  gemm_bt<0, 0><<<dim3(6, 32), 256, 0, stream>>>(ehsb, kvwb, kv_b, kvbuf, 768, 4096, 768, 768);

  rope_k_kernel<<<672, 256, 0, stream>>>(kvbuf);

  attn_kernel<<<dim3(7, 672), 256, 0, stream>>>(kvbuf, qbuf, tab);

  gemm256<1><<<1024, 512, 131072, stream>>>(qbuf, pwb, proj_b, out, 2048, 2048, 32760);
}

// Round 4
// 1047.880 us; speedup vs baseline: 1.1149x; 1.0346x over previous
//
#include <hip/hip_runtime.h>

typedef short bf16x8 __attribute__((ext_vector_type(8)));
typedef float f32x4 __attribute__((ext_vector_type(4)));

#define LN10000_32 0.2878231406211853f  // ln(10000)/32

__device__ __forceinline__ unsigned short f2bf(float f) {
  union { float f; unsigned int u; } v; v.f = f;
  unsigned int r = v.u + 0x7fffu + ((v.u >> 16) & 1u);
  return (unsigned short)(r >> 16);
}
__device__ __forceinline__ float bf2f(unsigned short h) {
  union { unsigned int u; float f; } v; v.u = ((unsigned int)h) << 16;
  return v.f;
}

__device__ __forceinline__ void stage16(const unsigned short* g, unsigned short* lds_base, int lane) {
#if __has_builtin(__builtin_amdgcn_global_load_lds)
  (void)lane;
  __builtin_amdgcn_global_load_lds((const __attribute__((address_space(1))) void*)g,
                                   (__attribute__((address_space(3))) void*)lds_base,
                                   16, 0, 0);
#else
  *(bf16x8*)((char*)lds_base + lane * 16) = *(const bf16x8*)g;
#endif
}

// ---------------- min/max of the two x_ref_attn_map rows ---------------------
__global__ void minmax_kernel(const float* __restrict__ xmap, float* __restrict__ mm) {
  __shared__ float red[4][256];
  int t = threadIdx.x;
  float mn0 = 3.4e38f, mx0 = -3.4e38f, mn1 = 3.4e38f, mx1 = -3.4e38f;
  for (int i = t; i < 32760; i += 256) {
    float a = xmap[i];          mn0 = fminf(mn0, a); mx0 = fmaxf(mx0, a);
    float b = xmap[32760 + i];  mn1 = fminf(mn1, b); mx1 = fmaxf(mx1, b);
  }
  red[0][t] = mn0; red[1][t] = mx0; red[2][t] = mn1; red[3][t] = mx1;
  __syncthreads();
  for (int s = 128; s > 0; s >>= 1) {
    if (t < s) {
      red[0][t] = fminf(red[0][t], red[0][t + s]);
      red[1][t] = fmaxf(red[1][t], red[1][t + s]);
      red[2][t] = fminf(red[2][t], red[2][t + s]);
      red[3][t] = fmaxf(red[3][t], red[3][t + s]);
    }
    __syncthreads();
  }
  if (t == 0) { mm[0] = red[0][0]; mm[1] = red[1][0]; mm[2] = red[2][0]; mm[3] = red[3][0]; }
}

// ---------------- normalized position -> cos/sin table (32760 x 32) ----------
__global__ void pos_table_kernel(const float* __restrict__ xmap, const float* __restrict__ mm,
                                 float2* __restrict__ tab) {
  int n = blockIdx.x * 256 + threadIdx.x;
  if (n >= 32760) return;
  float m0 = xmap[n], m1 = xmap[32760 + n];
  float pos;
  if (m1 > m0) pos = (m1 - mm[2]) / (mm[3] - mm[2] + 1e-8f) * 4.0f + 20.0f;
  else         pos = (m0 - mm[0]) / (mm[1] - mm[0] + 1e-8f) * 4.0f;
  #pragma unroll
  for (int j = 0; j < 32; j++) {
    float invf = __expf(-(float)j * LN10000_32);
    float f = pos * invf;
    float s, c;
    sincosf(f, &s, &c);
    tab[(long)n * 32 + j] = make_float2(c, s);
  }
}

// ---------------- casts -------------------------------------------------------
__global__ void cast_x_kernel(const float* __restrict__ src, unsigned short* __restrict__ dst) {
  int r = blockIdx.x;
  int c = threadIdx.x * 8;
  bf16x8 o;
  if (r < 32760) {
    const float4* s = (const float4*)(src + (long)r * 2048 + c);
    float4 a = s[0], b = s[1];
    o[0] = (short)f2bf(a.x); o[1] = (short)f2bf(a.y); o[2] = (short)f2bf(a.z); o[3] = (short)f2bf(a.w);
    o[4] = (short)f2bf(b.x); o[5] = (short)f2bf(b.y); o[6] = (short)f2bf(b.z); o[7] = (short)f2bf(b.w);
  } else {
    #pragma unroll
    for (int t = 0; t < 8; t++) o[t] = 0;
  }
  *(bf16x8*)(dst + (long)r * 2048 + c) = o;
}

__global__ void cast_flat_kernel(const float* __restrict__ src, unsigned short* __restrict__ dst, long n8) {
  long i = (long)blockIdx.x * 256 + threadIdx.x;
  if (i >= n8) return;
  const float4* s = (const float4*)(src + i * 8);
  float4 a = s[0], b = s[1];
  bf16x8 o;
  o[0] = (short)f2bf(a.x); o[1] = (short)f2bf(a.y); o[2] = (short)f2bf(a.z); o[3] = (short)f2bf(a.w);
  o[4] = (short)f2bf(b.x); o[5] = (short)f2bf(b.y); o[6] = (short)f2bf(b.z); o[7] = (short)f2bf(b.w);
  *(bf16x8*)(dst + i * 8) = o;
}

__global__ void cast_ehs_kernel(const float* __restrict__ src, unsigned short* __restrict__ dst) {
  int idx = blockIdx.x * 256 + threadIdx.x;
  int r = idx / 96, c = (idx % 96) * 8;
  bf16x8 o;
  if (r < 672) {
    const float4* s = (const float4*)(src + (long)r * 768 + c);
    float4 a = s[0], b = s[1];
    o[0] = (short)f2bf(a.x); o[1] = (short)f2bf(a.y); o[2] = (short)f2bf(a.z); o[3] = (short)f2bf(a.w);
    o[4] = (short)f2bf(b.x); o[5] = (short)f2bf(b.y); o[6] = (short)f2bf(b.z); o[7] = (short)f2bf(b.w);
  } else {
    #pragma unroll
    for (int t = 0; t < 8; t++) o[t] = 0;
  }
  *(bf16x8*)(dst + (long)r * 768 + c) = o;
}

// ---------------- small GEMM (128x128 m97-style) for KV projection -----------
template <int OUTF>
__global__ __launch_bounds__(256, 2)
void gemm_bt(const unsigned short* __restrict__ A, const unsigned short* __restrict__ B,
             const float* __restrict__ bias, void* __restrict__ C,
             int M, int N, int K, int M_valid) {
  __shared__ unsigned short As[128 * 32];
  __shared__ unsigned short Bs[128 * 32];
  int mt = blockIdx.x, nt = blockIdx.y;
  const int m0 = mt * 128;
  const int n0 = nt * 128;
  const int tid = threadIdx.x;
  const int wave = tid >> 6;
  const int lane = tid & 63;
  const int wr = wave >> 1, wc = wave & 1;
  const int lrow = lane >> 2, lcol = lane & 3;

  f32x4 acc[4][4];
  #pragma unroll
  for (int i = 0; i < 4; i++)
    #pragma unroll
    for (int j = 0; j < 4; j++) acc[i][j] = (f32x4){0.f, 0.f, 0.f, 0.f};

  const unsigned short* gA = A + (long)(m0 + wave * 32 + lrow) * K + lcol * 8;
  const unsigned short* gB = B + (long)(n0 + wave * 32 + lrow) * K + lcol * 8;
  unsigned short* lA0 = &As[wave * 1024];
  unsigned short* lA1 = &As[wave * 1024 + 512];
  unsigned short* lB0 = &Bs[wave * 1024];
  unsigned short* lB1 = &Bs[wave * 1024 + 512];

  for (int k0 = 0; k0 < K; k0 += 32) {
    stage16(gA + k0, lA0, lane);
    stage16(gA + k0 + 16 * K, lA1, lane);
    stage16(gB + k0, lB0, lane);
    stage16(gB + k0 + 16 * K, lB1, lane);
    __syncthreads();
    bf16x8 af[4], bfr[4];
    const int kq = (lane >> 4) * 8;
    const int rr = lane & 15;
    #pragma unroll
    for (int mi = 0; mi < 4; mi++) af[mi] = *(const bf16x8*)&As[(wr * 64 + mi * 16 + rr) * 32 + kq];
    #pragma unroll
    for (int ni = 0; ni < 4; ni++) bfr[ni] = *(const bf16x8*)&Bs[(wc * 64 + ni * 16 + rr) * 32 + kq];
    #pragma unroll
    for (int mi = 0; mi < 4; mi++)
      #pragma unroll
      for (int ni = 0; ni < 4; ni++)
        acc[mi][ni] = __builtin_amdgcn_mfma_f32_16x16x32_bf16(af[mi], bfr[ni], acc[mi][ni], 0, 0, 0);
    __syncthreads();
  }

  const int colL = lane & 15, rq = (lane >> 4) * 4;
  #pragma unroll
  for (int mi = 0; mi < 4; mi++) {
    #pragma unroll
    for (int ni = 0; ni < 4; ni++) {
      int col = n0 + wc * 64 + ni * 16 + colL;
      float bv = bias[col];
      #pragma unroll
      for (int r = 0; r < 4; r++) {
        int row = m0 + wr * 64 + mi * 16 + rq + r;
        if (row < M_valid) {
          float v = acc[mi][ni][r] + bv;
          if (OUTF) ((float*)C)[(long)row * N + col] = v;
          else      ((unsigned short*)C)[(long)row * N + col] = f2bf(v);
        }
      }
    }
  }
}

// ---------------- big GEMM: 256x256, BK=64, dbuf, 8-phase counted-vmcnt ------
// C[m,n] = sum_k A[m,k]*B[n,k] + bias[n].  8 waves (2M x 4N), wave tile 128x64.
// LDS 128 KiB: 2 bufs x (A 256x64 + B 256x64) bf16, halves of 128 rows.
// Per phase: ds_reads [12,4,8,0 pattern] + 2 global_load_lds + 2 barriers +
// setprio'd 16-MFMA cluster. vmcnt(4) only at phases 4 & 8 (gates verified:
// the 4 newest loads at each gate are exactly the not-yet-needed halves).
// Swizzle: 16B col-block cb stored at slot cb^(row&7); inverse applied on the
// per-lane global source (DMA dest stays linear), reads use the same XOR.
template <int OUTF>
__global__ __launch_bounds__(512, 2)
void gemm256(const unsigned short* __restrict__ A, const unsigned short* __restrict__ B,
             const float* __restrict__ bias, void* __restrict__ C,
             int K, int N, int M_valid) {
  extern __shared__ __align__(16) unsigned short lds[];  // 65536 ushorts
  const int NT = K >> 6;          // 64-wide K tiles (K=2048 -> 32)
  const int NI = NT >> 1;         // iters (2 tiles each)
  const int orig = blockIdx.x;
  const int cpx = (int)gridDim.x >> 3;
  const int wgid = (orig & 7) * cpx + (orig >> 3);
  const int nt = wgid & 7;
  const int mt = wgid >> 3;
  const int m0 = mt << 8, n0 = nt << 8;
  const int tid = threadIdx.x;
  const int w = tid >> 6, l = tid & 63;
  const int wr = w >> 2, wc = w & 3;
  const int i = l & 15, kq = l >> 4;

  // fragment-read constants
  const int swz0 = ((kq) ^ (i & 7)) * 8;        // k-step 0 16B-block, swizzled
  const int swz1 = ((4 + kq) ^ (i & 7)) * 8;    // k-step 1
  const int aoff = wr * 8192 + i * 64;                                   // + buf + mh*4096 + q*1024
  const int boff = 16384 + (wc >> 1) * 8192 + (wc & 1) * 4096 + i * 64;  // + buf + nf*1024

  // staging constants: lane covers row w*8+(l>>3), global col-block (l&7)^((l>>3)&7)
  const int srow = l >> 3;
  const int scb = ((l & 7) ^ srow) * 8;
  const int sdst = w * 512;
  const unsigned short* Asrc = A + (long)(m0 + w * 8 + srow) * K + scb;
  const unsigned short* Bsrc = B + (long)(n0 + w * 8 + srow) * K + scb;

  f32x4 acc[8][4];
  #pragma unroll
  for (int a_ = 0; a_ < 8; a_++)
    #pragma unroll
    for (int b_ = 0; b_ < 4; b_++) acc[a_][b_] = (f32x4){0.f, 0.f, 0.f, 0.f};

  bf16x8 a[4][2], b[4][2];

#define BAR __builtin_amdgcn_s_barrier()
#define VM4 asm volatile("s_waitcnt vmcnt(4)" ::: "memory")
#define VM0 asm volatile("s_waitcnt vmcnt(0)" ::: "memory")

#define STG_A(T, h) do { \
    const unsigned short* s_ = Asrc + (long)((h) * 128) * K + (T) * 64; \
    unsigned short* d_ = lds + (((T) & 1) << 15) + ((h) << 13) + sdst; \
    stage16(s_, d_, l); \
    stage16(s_ + (long)64 * K, d_ + 4096, l); \
  } while (0)
#define STG_B(T, h) do { \
    const unsigned short* s_ = Bsrc + (long)((h) * 128) * K + (T) * 64; \
    unsigned short* d_ = lds + (((T) & 1) << 15) + 16384 + ((h) << 13) + sdst; \
    stage16(s_, d_, l); \
    stage16(s_ + (long)64 * K, d_ + 4096, l); \
  } while (0)

#define RD_A(bufo, mh) do { \
    const unsigned short* p_ = lds + (bufo) + aoff + (mh) * 4096; \
    a[0][0] = *(const bf16x8*)(p_ + swz0);        a[0][1] = *(const bf16x8*)(p_ + swz1); \
    a[1][0] = *(const bf16x8*)(p_ + 1024 + swz0); a[1][1] = *(const bf16x8*)(p_ + 1024 + swz1); \
    a[2][0] = *(const bf16x8*)(p_ + 2048 + swz0); a[2][1] = *(const bf16x8*)(p_ + 2048 + swz1); \
    a[3][0] = *(const bf16x8*)(p_ + 3072 + swz0); a[3][1] = *(const bf16x8*)(p_ + 3072 + swz1); \
  } while (0)
#define RD_B(bufo, nf) do { \
    const unsigned short* p_ = lds + (bufo) + boff + (nf) * 1024; \
    b[nf][0] = *(const bf16x8*)(p_ + swz0); \
    b[nf][1] = *(const bf16x8*)(p_ + swz1); \
  } while (0)

#define MMQ(AB, N0, N1) do { \
    __builtin_amdgcn_s_setprio(1); \
    _Pragma("unroll") \
    for (int q_ = 0; q_ < 4; q_++) { \
      acc[(AB) + q_][N0] = __builtin_amdgcn_mfma_f32_16x16x32_bf16(a[q_][0], b[N0][0], acc[(AB) + q_][N0], 0, 0, 0); \
      acc[(AB) + q_][N1] = __builtin_amdgcn_mfma_f32_16x16x32_bf16(a[q_][0], b[N1][0], acc[(AB) + q_][N1], 0, 0, 0); \
    } \
    _Pragma("unroll") \
    for (int q_ = 0; q_ < 4; q_++) { \
      acc[(AB) + q_][N0] = __builtin_amdgcn_mfma_f32_16x16x32_bf16(a[q_][1], b[N0][1], acc[(AB) + q_][N0], 0, 0, 0); \
      acc[(AB) + q_][N1] = __builtin_amdgcn_mfma_f32_16x16x32_bf16(a[q_][1], b[N1][1], acc[(AB) + q_][N1], 0, 0, 0); \
    } \
    __builtin_amdgcn_s_setprio(0); \
  } while (0)

#define GEMM_ITER(T0v, T1v, FULL, GATEP4, GATEP8) do { \
    const int T0_ = (T0v), T1_ = (T1v); \
    /* p1 */ RD_A(0, 0); RD_B(0, 0); RD_B(0, 1); STG_B(T1_, 1); BAR; MMQ(0, 0, 1); BAR; \
    /* p2 */ RD_B(0, 2); RD_B(0, 3); STG_A(T1_, 1); BAR; MMQ(0, 2, 3); BAR; \
    /* p3 */ RD_A(0, 1); if (FULL) { STG_B(T0_ + 2, 0); } BAR; MMQ(4, 2, 3); BAR; \
    /* p4 */ if (FULL) { STG_A(T0_ + 2, 0); } GATEP4; BAR; MMQ(4, 0, 1); BAR; \
    /* p5 */ RD_A(32768, 0); RD_B(32768, 0); RD_B(32768, 1); if (FULL) { STG_B(T0_ + 2, 1); } BAR; MMQ(0, 0, 1); BAR; \
    /* p6 */ RD_B(32768, 2); RD_B(32768, 3); if (FULL) { STG_A(T0_ + 2, 1); } BAR; MMQ(0, 2, 3); BAR; \
    /* p7 */ RD_A(32768, 1); if (FULL) { STG_B(T1_ + 2, 0); } BAR; MMQ(4, 2, 3); BAR; \
    /* p8 */ if (FULL) { STG_A(T1_ + 2, 0); } GATEP8; BAR; MMQ(4, 0, 1); BAR; \
  } while (0)

  // prologue: tile0 fully + tile1 h0 halves, in steady-state order
  STG_B(0, 0); STG_A(0, 0); STG_B(0, 1); STG_A(0, 1);
  STG_B(1, 0); STG_A(1, 0);
  VM4; BAR;

  for (int j = 0; j < NI - 1; ++j) {
    GEMM_ITER(2 * j, 2 * j + 1, 1, VM4, VM4);
  }
  GEMM_ITER(NT - 2, NT - 1, 0, VM0, (void)0);

#undef GEMM_ITER
#undef MMQ
#undef RD_B
#undef RD_A
#undef STG_B
#undef STG_A
#undef VM0
#undef VM4
#undef BAR

  // epilogue
  #pragma unroll
  for (int nf = 0; nf < 4; nf++) {
    int col = n0 + wc * 64 + nf * 16 + i;
    float bv = bias[col];
    #pragma unroll
    for (int mf = 0; mf < 8; mf++) {
      int rowb = m0 + wr * 128 + mf * 16 + kq * 4;
      #pragma unroll
      for (int r = 0; r < 4; r++) {
        int row = rowb + r;
        if (row < M_valid) {
          float v = acc[mf][nf][r] + bv;
          if (OUTF) ((float*)C)[(long)row * N + col] = v;
          else      ((unsigned short*)C)[(long)row * N + col] = f2bf(v);
        }
      }
    }
  }
}

// ---------------- RoPE on K (in place, fixed positions 2 / 22) ----------------
__global__ void rope_k_kernel(unsigned short* __restrict__ kv) {
  int r = blockIdx.x;
  int c = threadIdx.x * 8;
  float pos = ((r & 31) < 16) ? 2.0f : 22.0f;
  unsigned short* p = kv + (long)r * 4096 + c;
  bf16x8 v = *(const bf16x8*)p;
  int jb = (c & 63) >> 1;
  bf16x8 o;
  #pragma unroll
  for (int t = 0; t < 4; t++) {
    float invf = __expf(-(float)(jb + t) * LN10000_32);
    float f = pos * invf;
    float s_, c_;
    sincosf(f, &s_, &c_);
    float x1 = bf2f((unsigned short)v[2 * t]);
    float x2 = bf2f((unsigned short)v[2 * t + 1]);
    o[2 * t]     = (short)f2bf(x1 * c_ - x2 * s_);
    o[2 * t + 1] = (short)f2bf(x1 * s_ + x2 * c_);
  }
  *(bf16x8*)p = o;
}

// ---------------- attention: RoPE(Q) fused + 32 keys, VALU, in place ----------
__global__ __launch_bounds__(256)
void attn_kernel(const unsigned short* __restrict__ kv, unsigned short* __restrict__ q,
                 const float2* __restrict__ tab) {
  __shared__ float Ks[2048];
  __shared__ float Vs[2048];
  const int bh = blockIdx.y;
  const int b = bh >> 5, h = bh & 31;
  const int tid = threadIdx.x;
  for (int i = tid; i < 2048; i += 256) {
    int a = i >> 6, d = i & 63;
    long off = ((long)(b * 32 + a)) * 4096 + h * 64 + d;
    Ks[i] = bf2f(kv[off]);
    Vs[i] = bf2f(kv[off + 2048]);
  }
  __syncthreads();
  int s = blockIdx.x * 256 + tid;
  if (s >= 1560) return;
  const long row = (long)b * 1560 + s;
  unsigned short* qp = q + row * 2048 + h * 64;
  float qr[64];
  #pragma unroll
  for (int i = 0; i < 8; i++) {
    bf16x8 v = *(const bf16x8*)(qp + i * 8);
    #pragma unroll
    for (int j = 0; j < 8; j++) qr[i * 8 + j] = bf2f((unsigned short)v[j]);
  }
  const float2* trow = tab + row * 32;
  #pragma unroll
  for (int j = 0; j < 32; j++) {
    float2 cs = trow[j];
    float x1 = qr[2 * j], x2 = qr[2 * j + 1];
    qr[2 * j]     = x1 * cs.x - x2 * cs.y;
    qr[2 * j + 1] = x1 * cs.y + x2 * cs.x;
  }
  float sc[32];
  float mx = -3.4e38f;
  #pragma unroll
  for (int a = 0; a < 32; a++) {
    float acc = 0.f;
    #pragma unroll
    for (int d = 0; d < 64; d++) acc = fmaf(qr[d], Ks[a * 64 + d], acc);
    acc *= 0.125f;
    sc[a] = acc;
    mx = fmaxf(mx, acc);
  }
  float sum = 0.f;
  #pragma unroll
  for (int a = 0; a < 32; a++) { float e = __expf(sc[a] - mx); sc[a] = e; sum += e; }
  float inv = 1.f / sum;
  float outr[64];
  #pragma unroll
  for (int d = 0; d < 64; d++) outr[d] = 0.f;
  #pragma unroll
  for (int a = 0; a < 32; a++) {
    float p = sc[a] * inv;
    #pragma unroll
    for (int d = 0; d < 64; d++) outr[d] = fmaf(p, Vs[a * 64 + d], outr[d]);
  }
  #pragma unroll
  for (int i = 0; i < 8; i++) {
    bf16x8 v;
    #pragma unroll
    for (int j = 0; j < 8; j++) v[j] = (short)f2bf(outr[i * 8 + j]);
    *(bf16x8*)(qp + i * 8) = v;
  }
}

// ---------------- launch ------------------------------------------------------
extern "C" void kernel_launch(void* const* d_in, const int* in_sizes, int n_in,
                              void* d_out, int out_size, void* d_ws, size_t ws_size,
                              hipStream_t stream) {
  const float* x      = (const float*)d_in[0];
  const float* ehs    = (const float*)d_in[1];
  const float* xmap   = (const float*)d_in[2];
  const float* q_w    = (const float*)d_in[3];
  const float* q_b    = (const float*)d_in[4];
  const float* kv_w   = (const float*)d_in[5];
  const float* kv_b   = (const float*)d_in[6];
  const float* proj_w = (const float*)d_in[7];
  const float* proj_b = (const float*)d_in[8];
  float* out = (float*)d_out;

  char* ws = (char*)d_ws;
  float*          mm    = (float*)(ws + 0);
  float2*         tab   = (float2*)(ws + 256);
  unsigned short* qbuf  = (unsigned short*)(ws + 8388864);
  unsigned short* kvbuf = (unsigned short*)(ws + 142606592);
  unsigned short* ehsb  = (unsigned short*)(ws + 148898048);
  unsigned short* qwb   = (unsigned short*)(ws + 150077696);
  unsigned short* kvwb  = (unsigned short*)(ws + 158466304);
  unsigned short* pwb   = (unsigned short*)(ws + 164757760);
  unsigned short* xb    = (unsigned short*)d_out;

  (void)hipFuncSetAttribute((const void*)gemm256<0>, hipFuncAttributeMaxDynamicSharedMemorySize, 131072);
  (void)hipFuncSetAttribute((const void*)gemm256<1>, hipFuncAttributeMaxDynamicSharedMemorySize, 131072);

  minmax_kernel<<<1, 256, 0, stream>>>(xmap, mm);
  pos_table_kernel<<<128, 256, 0, stream>>>(xmap, mm, tab);
  cast_x_kernel<<<32768, 256, 0, stream>>>(x, xb);
  cast_flat_kernel<<<2048, 256, 0, stream>>>(q_w, qwb, 524288);
  cast_flat_kernel<<<1536, 256, 0, stream>>>(kv_w, kvwb, 393216);
  cast_flat_kernel<<<2048, 256, 0, stream>>>(proj_w, pwb, 524288);
  cast_ehs_kernel<<<288, 256, 0, stream>>>(ehs, ehsb);

  gemm256<0><<<1024, 512, 131072, stream>>>(xb, qwb, q_b, qbuf, 2048, 2048, 32768);
  gemm_bt<0><<<dim3(6, 32), 256, 0, stream>>>(ehsb, kvwb, kv_b, kvbuf, 768, 4096, 768, 768);

  rope_k_kernel<<<672, 256, 0, stream>>>(kvbuf);

  attn_kernel<<<dim3(7, 672), 256, 0, stream>>>(kvbuf, qbuf, tab);

  gemm256<1><<<1024, 512, 131072, stream>>>(qbuf, pwb, proj_b, out, 2048, 2048, 32760);
}